// Round 2
// baseline (2172.201 us; speedup 1.0000x reference)
//
#include <hip/hip_runtime.h>
#include <hip/hip_bf16.h>

#define E_TOT 160000
#define NN    10000
#define EPB   16      // edges per block

__device__ __forceinline__ float sigmoidf_(float x) { return 1.0f / (1.0f + __expf(-x)); }
__device__ __forceinline__ float siluf_(float x) { return x * sigmoidf_(x); }

// Fused per-edge GCP kernel: 16 edges / block, 256 threads, all fp32.
// All intermediates in LDS. Weights read from global (L1/L2-hot).
// Aggregation: fp32 atomicAdd directly into d_out (zeroed first).
__global__ __launch_bounds__(256) void edge_kernel(
    const float* __restrict__ node_s, const float* __restrict__ node_v,
    const float* __restrict__ edge_s, const float* __restrict__ edge_v,
    const float* __restrict__ frames,
    const float* __restrict__ W1d,  const float* __restrict__ W1f,
    const float* __restrict__ W1so, const float* __restrict__ b1so,
    const float* __restrict__ W1up, const float* __restrict__ W1g, const float* __restrict__ b1g,
    const float* __restrict__ W2d,  const float* __restrict__ W2f,
    const float* __restrict__ W2so, const float* __restrict__ b2so,
    const float* __restrict__ W2up, const float* __restrict__ W2g, const float* __restrict__ b2g,
    const float* __restrict__ attW, const float* __restrict__ attb,
    const void* __restrict__ eidx, float* __restrict__ out)
{
    __shared__ float mT[336][16];      // merged1 transposed [k][e]
    __shared__ float mv[16][36][3];    // gathered vector inputs
    __shared__ float fr[16][9];        // frames
    __shared__ float vhid[16][3][36];  // layer-1 v hidden
    __shared__ float vfr[16][3][3];    // layer-1 v frames
    __shared__ float s1[16][132];      // silu(s_out1)  (padded)
    __shared__ float s2b[16][132];     // silu(s_out2)
    __shared__ float m2T[160][16];     // merged2 transposed [k][e]
    __shared__ float gbuf[16][16];     // gate (reused layer1 -> layer2)
    __shared__ float v1[16][16][3];    // gated v_out1, then final v
    __shared__ float v2b[16][16][3];   // raw v_out2
    __shared__ float vhid2[16][3][16];
    __shared__ float vfr2[16][3][3];
    __shared__ float attn[16];
    __shared__ int   rowb[16], colb[16];

    const int t  = threadIdx.x;
    const int eg = blockIdx.x * EPB;

    // ---- index load, with runtime int32/int64 detection ----
    // int64 values < 10000 => all high (odd) 32-bit words are 0.
    {
        const int* pi = (const int*)eidx;
        const long long* pl = (const long long*)eidx;
        bool is64 = ((pi[1] | pi[3] | pi[5] | pi[7] |
                      pi[9] | pi[11] | pi[13] | pi[15]) == 0);
        if (t < EPB) {
            int r, c;
            if (is64) { r = (int)pl[eg + t]; c = (int)pl[E_TOT + eg + t]; }
            else      { r = pi[eg + t];      c = pi[E_TOT + eg + t];      }
            rowb[t] = r; colb[t] = c;
        }
    }
    __syncthreads();

    // ---- Phase A: gather scalar + vector inputs ----
    for (int i = t; i < 16 * 288; i += 256) {
        int e = i / 288, k = i - e * 288;
        float v;
        if (k < 128)      v = node_s[rowb[e] * 128 + k];
        else if (k < 160) v = edge_s[(eg + e) * 32 + (k - 128)];
        else              v = node_s[colb[e] * 128 + (k - 160)];
        mT[k][e] = v;
    }
    for (int i = t; i < 16 * 108; i += 256) {
        int e = i / 108, r = i - e * 108, c = r / 3, sp = r - c * 3;
        float v;
        if (c < 16)      v = node_v[rowb[e] * 48 + c * 3 + sp];
        else if (c < 20) v = edge_v[(eg + e) * 12 + (c - 16) * 3 + sp];
        else             v = node_v[colb[e] * 48 + (c - 20) * 3 + sp];
        mv[e][c][sp] = v;
    }
    for (int i = t; i < 144; i += 256) {
        int e = i / 9, j = i - e * 9;
        fr[e][j] = frames[(eg + e) * 9 + j];
    }
    __syncthreads();

    // ---- Phase B: v_hid1 = v_pre @ Wdown1, v_frames1 = v_pre @ Wdf1 ----
    for (int i = t; i < 16 * 3 * 39; i += 256) {   // 1872 items
        int e = i / 117, r = i - e * 117, sp = r / 39, h = r - sp * 39;
        float sum = 0.f;
        if (h < 36) {
            #pragma unroll 4
            for (int c = 0; c < 36; ++c) sum = fmaf(mv[e][c][sp], W1d[c * 36 + h], sum);
            vhid[e][sp][h] = sum;
        } else {
            int a = h - 36;
            #pragma unroll 4
            for (int c = 0; c < 36; ++c) sum = fmaf(mv[e][c][sp], W1f[c * 3 + a], sum);
            vfr[e][sp][a] = sum;
        }
    }
    __syncthreads();

    // ---- Phase C: v_norm1 and local1 into merged1 rows 288..332 ----
    for (int i = t; i < 576 + 144; i += 256) {
        if (i < 576) {
            int e = i / 36, h = i - e * 36;
            float a0 = vhid[e][0][h], a1 = vhid[e][1][h], a2 = vhid[e][2][h];
            mT[288 + h][e] = sqrtf(fmaf(a0, a0, fmaf(a1, a1, fmaf(a2, a2, 1e-8f))));
        } else {
            int j = i - 576;
            int e = j / 9, r = j - e * 9, a = r / 3, b = r - a * 3;
            // local[3a+b] = sum_k frames[b][k] * v_frames[k][a]
            mT[324 + r][e] = fr[e][b * 3 + 0] * vfr[e][0][a]
                           + fr[e][b * 3 + 1] * vfr[e][1][a]
                           + fr[e][b * 3 + 2] * vfr[e][2][a];
        }
    }
    __syncthreads();

    // ---- Phase D: s_out1 = merged1 @ Wso1 + b, s1 = silu ----
    {
        const int e = t & 15, n0 = (t >> 4) * 8;
        float a[8];
        #pragma unroll
        for (int j = 0; j < 8; ++j) a[j] = 0.f;
        #pragma unroll 2
        for (int k = 0; k < 333; ++k) {
            const float4* wp = (const float4*)(W1so + k * 128 + n0);
            float4 w0 = wp[0], w1 = wp[1];
            float m = mT[k][e];
            a[0] = fmaf(w0.x, m, a[0]); a[1] = fmaf(w0.y, m, a[1]);
            a[2] = fmaf(w0.z, m, a[2]); a[3] = fmaf(w0.w, m, a[3]);
            a[4] = fmaf(w1.x, m, a[4]); a[5] = fmaf(w1.y, m, a[5]);
            a[6] = fmaf(w1.z, m, a[6]); a[7] = fmaf(w1.w, m, a[7]);
        }
        #pragma unroll
        for (int j = 0; j < 8; ++j) {
            float sl = siluf_(a[j] + b1so[n0 + j]);
            s1[e][n0 + j] = sl;
            m2T[n0 + j][e] = sl;   // merged2 scalar part (k-major)
        }
    }
    __syncthreads();

    // ---- Phase E: gate1 and raw v_out1 ----
    {
        const int e = t & 15, o = t >> 4;
        float sum = b1g[o];
        #pragma unroll 4
        for (int c = 0; c < 128; ++c) sum = fmaf(s1[e][c], W1g[c * 16 + o], sum);
        gbuf[e][o] = sigmoidf_(sum);
    }
    for (int i = t; i < 768; i += 256) {
        int e = i / 48, r = i - e * 48, o = r / 3, sp = r - o * 3;
        float sum = 0.f;
        #pragma unroll 4
        for (int h = 0; h < 36; ++h) sum = fmaf(vhid[e][sp][h], W1up[h * 16 + o], sum);
        v1[e][o][sp] = sum;
    }
    __syncthreads();

    // ---- Phase F: apply gate1 ----
    for (int i = t; i < 768; i += 256) {
        int e = i / 48, r = i - e * 48, o = r / 3, sp = r - o * 3;
        v1[e][o][sp] *= gbuf[e][o];
    }
    __syncthreads();

    // ---- Phase G: v_hid2 / v_frames2 ----
    for (int i = t; i < 16 * 3 * 19; i += 256) {   // 912 items
        int e = i / 57, r = i - e * 57, sp = r / 19, h = r - sp * 19;
        float sum = 0.f;
        if (h < 16) {
            #pragma unroll
            for (int c = 0; c < 16; ++c) sum = fmaf(v1[e][c][sp], W2d[c * 16 + h], sum);
            vhid2[e][sp][h] = sum;
        } else {
            int a = h - 16;
            #pragma unroll
            for (int c = 0; c < 16; ++c) sum = fmaf(v1[e][c][sp], W2f[c * 3 + a], sum);
            vfr2[e][sp][a] = sum;
        }
    }
    __syncthreads();

    // ---- Phase H: v_norm2 and local2 into merged2 rows 128..152 ----
    for (int i = t; i < 256 + 144; i += 256) {
        if (i < 256) {
            int e = i >> 4, h = i & 15;
            float a0 = vhid2[e][0][h], a1 = vhid2[e][1][h], a2 = vhid2[e][2][h];
            m2T[128 + h][e] = sqrtf(fmaf(a0, a0, fmaf(a1, a1, fmaf(a2, a2, 1e-8f))));
        } else {
            int j = i - 256;
            int e = j / 9, r = j - e * 9, a = r / 3, b = r - a * 3;
            m2T[144 + r][e] = fr[e][b * 3 + 0] * vfr2[e][0][a]
                            + fr[e][b * 3 + 1] * vfr2[e][1][a]
                            + fr[e][b * 3 + 2] * vfr2[e][2][a];
        }
    }
    __syncthreads();

    // ---- Phase I: s_out2, s2 = silu ----
    {
        const int e = t & 15, n0 = (t >> 4) * 8;
        float a[8];
        #pragma unroll
        for (int j = 0; j < 8; ++j) a[j] = 0.f;
        #pragma unroll 2
        for (int k = 0; k < 153; ++k) {
            const float4* wp = (const float4*)(W2so + k * 128 + n0);
            float4 w0 = wp[0], w1 = wp[1];
            float m = m2T[k][e];
            a[0] = fmaf(w0.x, m, a[0]); a[1] = fmaf(w0.y, m, a[1]);
            a[2] = fmaf(w0.z, m, a[2]); a[3] = fmaf(w0.w, m, a[3]);
            a[4] = fmaf(w1.x, m, a[4]); a[5] = fmaf(w1.y, m, a[5]);
            a[6] = fmaf(w1.z, m, a[6]); a[7] = fmaf(w1.w, m, a[7]);
        }
        #pragma unroll
        for (int j = 0; j < 8; ++j) s2b[e][n0 + j] = siluf_(a[j] + b2so[n0 + j]);
    }
    __syncthreads();

    // ---- Phase J: gate2 and raw v_out2 ----
    {
        const int e = t & 15, o = t >> 4;
        float sum = b2g[o];
        #pragma unroll 4
        for (int c = 0; c < 128; ++c) sum = fmaf(s2b[e][c], W2g[c * 16 + o], sum);
        gbuf[e][o] = sigmoidf_(sum);
    }
    for (int i = t; i < 768; i += 256) {
        int e = i / 48, r = i - e * 48, o = r / 3, sp = r - o * 3;
        float sum = 0.f;
        #pragma unroll
        for (int h = 0; h < 16; ++h) sum = fmaf(vhid2[e][sp][h], W2up[h * 16 + o], sum);
        v2b[e][o][sp] = sum;
    }
    __syncthreads();

    // ---- Phase K: residual v, attention scalar ----
    for (int i = t; i < 768; i += 256) {
        int e = i / 48, r = i - e * 48, o = r / 3, sp = r - o * 3;
        v1[e][o][sp] = fmaf(v2b[e][o][sp], gbuf[e][o], v1[e][o][sp]);
    }
    if (t < 16) {
        float sum = attb[0];
        #pragma unroll 4
        for (int c = 0; c < 128; ++c) sum = fmaf(s1[t][c] + s2b[t][c], attW[c], sum);
        attn[t] = sigmoidf_(sum);
    }
    __syncthreads();

    // ---- Phase L: scatter-add to destination nodes (fp32 atomics) ----
    for (int i = t; i < 16 * 176; i += 256) {
        int e = i / 176, j = i - e * 176;
        float val;
        if (j < 128) {
            val = (s1[e][j] + s2b[e][j]) * attn[e];
        } else {
            int r = j - 128, o = r / 3, sp = r - o * 3;
            val = v1[e][o][sp];
        }
        atomicAdd(&out[rowb[e] * 176 + j], val);
    }
}

extern "C" void kernel_launch(void* const* d_in, const int* in_sizes, int n_in,
                              void* d_out, int out_size, void* d_ws, size_t ws_size,
                              hipStream_t stream) {
    const float* node_s = (const float*)d_in[0];
    const float* node_v = (const float*)d_in[1];
    const float* edge_s = (const float*)d_in[2];
    const float* edge_v = (const float*)d_in[3];
    const float* frames = (const float*)d_in[4];
    const float* W1d  = (const float*)d_in[5];
    const float* W1f  = (const float*)d_in[6];
    const float* W1so = (const float*)d_in[7];
    const float* b1so = (const float*)d_in[8];
    const float* W1up = (const float*)d_in[9];
    const float* W1g  = (const float*)d_in[10];
    const float* b1g  = (const float*)d_in[11];
    const float* W2d  = (const float*)d_in[12];
    const float* W2f  = (const float*)d_in[13];
    const float* W2so = (const float*)d_in[14];
    const float* b2so = (const float*)d_in[15];
    const float* W2up = (const float*)d_in[16];
    const float* W2g  = (const float*)d_in[17];
    const float* b2g  = (const float*)d_in[18];
    const float* attW = (const float*)d_in[19];
    const float* attb = (const float*)d_in[20];
    const void*  eidx = d_in[21];

    float* out = (float*)d_out;

    // d_out is poisoned before every timed launch — zero it ourselves.
    hipMemsetAsync(out, 0, (size_t)out_size * sizeof(float), stream);

    edge_kernel<<<E_TOT / EPB, 256, 0, stream>>>(
        node_s, node_v, edge_s, edge_v, frames,
        W1d, W1f, W1so, b1so, W1up, W1g, b1g,
        W2d, W2f, W2so, b2so, W2up, W2g, b2g,
        attW, attb, eidx, out);
}

// Round 3
// 930.376 us; speedup vs baseline: 2.3348x; 2.3348x over previous
//
#include <hip/hip_runtime.h>
#include <hip/hip_bf16.h>

#define E_TOT 160000
#define NN    10000
#define EPB   32      // edges per block (2 MFMA M-tiles of 16)

typedef unsigned short ushortT;
typedef __attribute__((ext_vector_type(8))) short short8;
typedef __attribute__((ext_vector_type(4))) float f32x4;

__device__ __forceinline__ float sigmoidf_(float x) { return 1.0f / (1.0f + __expf(-x)); }
__device__ __forceinline__ float siluf_(float x) { return x * sigmoidf_(x); }

// fp32 -> bf16 (round-to-nearest-even), as raw ushort
__device__ __forceinline__ ushortT f2b(float f) {
    union { float f; unsigned int u; } x; x.f = f;
    unsigned int r = x.u + 0x7fffu + ((x.u >> 16) & 1u);
    return (ushortT)(r >> 16);
}
__device__ __forceinline__ float b2f(ushortT h) {
    union { unsigned int u; float f; } x; x.u = ((unsigned int)h) << 16; return x.f;
}

// Prep: transpose + bf16-cast the two big GEMM weights into workspace,
// zero-padded along K so the MFMA K-loop can run over the padded range.
//   W1soT: [128][352] bf16  (from W1so [333][128] fp32)   at ws ushort offset 0
//   W2soT: [128][160] bf16  (from W2so [153][128] fp32)   at ws ushort offset 45056
__global__ __launch_bounds__(256) void prep_kernel(
    const float* __restrict__ W1so, const float* __restrict__ W2so,
    ushortT* __restrict__ ws)
{
    int i = blockIdx.x * 256 + threadIdx.x;   // grid 256*256 = 65536 = 45056+20480
    if (i < 45056) {
        int n = i / 352, k = i - n * 352;
        ws[i] = (k < 333) ? f2b(W1so[k * 128 + n]) : (ushortT)0;
    } else {
        int j = i - 45056;
        int n = j / 160, k = j - n * 160;
        ws[i] = (k < 153) ? f2b(W2so[k * 128 + n]) : (ushortT)0;
    }
}

// Fused per-edge GCP kernel: 32 edges / block, 256 threads (4 waves).
// Big GEMMs (phases D, I) on bf16 MFMA; everything else VALU fp32.
// LDS manually overlaid (53,888 B -> 3 blocks/CU).
__global__ __launch_bounds__(256, 3) void edge_kernel(
    const float* __restrict__ node_s, const float* __restrict__ node_v,
    const float* __restrict__ edge_s, const float* __restrict__ edge_v,
    const float* __restrict__ frames,
    const float* __restrict__ W1d,  const float* __restrict__ W1f,
    const float* __restrict__ b1so,
    const float* __restrict__ W1up, const float* __restrict__ W1g, const float* __restrict__ b1g,
    const float* __restrict__ W2d,  const float* __restrict__ W2f,
    const float* __restrict__ b2so,
    const float* __restrict__ W2up, const float* __restrict__ W2g, const float* __restrict__ b2g,
    const float* __restrict__ attW, const float* __restrict__ attb,
    const ushortT* __restrict__ W1T, const ushortT* __restrict__ W2T,
    const void* __restrict__ eidx, float* __restrict__ out)
{
    // ---- manual LDS overlay ----
    __shared__ __align__(16) char smem[53888];
    ushortT* msh  = (ushortT*)smem;             // [32][376] bf16 merged1 (dead after D)
    float*   gbuf = (float*)smem;               // [32][16]   (aliases msh, live E..)
    float*   v1   = (float*)(smem + 2048);      // [32][16][3]
    float*   vhid2= (float*)(smem + 8192);      // [32][3][16]
    float*   vfr2 = (float*)(smem + 14336);     // [32][3][3]
    ushortT* mv   = (ushortT*)(smem + 24064);   // [32][3][40] bf16 (dead after B)
    ushortT* s2s  = (ushortT*)(smem + 24064);   // [32][136] bf16 (aliases mv, live I..)
    ushortT* vhid = (ushortT*)(smem + 32768);   // [32][3][40] bf16
    float*   vfr  = (float*)(smem + 40448);     // [32][3][3]
    ushortT* m2   = (ushortT*)(smem + 41600);   // [32][168] bf16 merged2 (rows 0..127 = s1)
    float*   fr   = (float*)(smem + 52352);     // [32][9]
    float*   attn = (float*)(smem + 53504);     // [32]
    int*     rowb = (int*)(smem + 53632);       // [32]
    int*     colb = (int*)(smem + 53760);       // [32]

    const int t  = threadIdx.x;
    const int eg = blockIdx.x * EPB;

    // ---- index load, runtime int32/int64 detection ----
    {
        const int* pi = (const int*)eidx;
        const long long* pl = (const long long*)eidx;
        bool is64 = ((pi[1] | pi[3] | pi[5] | pi[7] |
                      pi[9] | pi[11] | pi[13] | pi[15]) == 0);
        if (t < EPB) {
            int r, c;
            if (is64) { r = (int)pl[eg + t]; c = (int)pl[E_TOT + eg + t]; }
            else      { r = pi[eg + t];      c = pi[E_TOT + eg + t];      }
            rowb[t] = r; colb[t] = c;
        }
    }
    __syncthreads();

    // ---- Phase A: gather (scalar as bf16 into msh, vectors into mv, frames) ----
    for (int i = t; i < 32 * 72; i += 256) {       // merged1 scalar part, float4 loads
        int e = i / 72, q = i - e * 72;
        float4 v;
        if (q < 32)      v = ((const float4*)node_s)[rowb[e] * 32 + q];
        else if (q < 40) v = ((const float4*)edge_s)[(eg + e) * 8 + (q - 32)];
        else             v = ((const float4*)node_s)[colb[e] * 32 + (q - 40)];
        unsigned int lo = ((unsigned int)f2b(v.y) << 16) | f2b(v.x);
        unsigned int hi = ((unsigned int)f2b(v.w) << 16) | f2b(v.z);
        *(uint2*)(msh + e * 376 + q * 4) = make_uint2(lo, hi);
    }
    for (int i = t; i < 32 * 20; i += 256) {       // zero K-pad rows 333..351
        int e = i / 20, k = 333 + (i - e * 20);
        if (k < 352) msh[e * 376 + k] = 0;
    }
    for (int i = t; i < 32 * 108; i += 256) {      // vector gather, transposed to [e][sp][c]
        int e = i / 108, r = i - e * 108, c = r / 3, sp = r - c * 3;
        float v;
        if (c < 16)      v = node_v[rowb[e] * 48 + c * 3 + sp];
        else if (c < 20) v = edge_v[(eg + e) * 12 + (c - 16) * 3 + sp];
        else             v = node_v[colb[e] * 48 + (c - 20) * 3 + sp];
        mv[e * 120 + sp * 40 + c] = f2b(v);
    }
    for (int i = t; i < 288; i += 256) {
        int e = i / 9, j = i - e * 9;
        fr[e * 9 + j] = frames[(eg + e) * 9 + j];
    }
    __syncthreads();

    // ---- Phase B: v_hid1 / v_frames1 ----
    for (int i = t; i < 3744; i += 256) {          // 32*3*39
        int e = i / 117, r = i - e * 117, sp = r / 39, h = r - sp * 39;
        const ushortT* mvp = mv + e * 120 + sp * 40;
        float sum = 0.f;
        if (h < 36) {
            #pragma unroll 4
            for (int c = 0; c < 36; ++c) sum = fmaf(b2f(mvp[c]), W1d[c * 36 + h], sum);
            vhid[e * 120 + sp * 40 + h] = f2b(sum);
        } else {
            int a = h - 36;
            #pragma unroll 4
            for (int c = 0; c < 36; ++c) sum = fmaf(b2f(mvp[c]), W1f[c * 3 + a], sum);
            vfr[e * 9 + sp * 3 + a] = sum;
        }
    }
    __syncthreads();

    // ---- Phase C: v_norm1 + local1 into msh rows 288..332 ----
    for (int i = t; i < 1440; i += 256) {
        if (i < 1152) {
            int e = i / 36, h = i - e * 36;
            float a0 = b2f(vhid[e * 120 + h]);
            float a1 = b2f(vhid[e * 120 + 40 + h]);
            float a2 = b2f(vhid[e * 120 + 80 + h]);
            msh[e * 376 + 288 + h] = f2b(sqrtf(fmaf(a0, a0, fmaf(a1, a1, fmaf(a2, a2, 1e-8f)))));
        } else {
            int j = i - 1152, e = j / 9, r = j - e * 9, a = r / 3, b = r - a * 3;
            float x = fr[e * 9 + b * 3 + 0] * vfr[e * 9 + 0 + a]
                    + fr[e * 9 + b * 3 + 1] * vfr[e * 9 + 3 + a]
                    + fr[e * 9 + b * 3 + 2] * vfr[e * 9 + 6 + a];
            msh[e * 376 + 324 + r] = f2b(x);
        }
    }
    __syncthreads();

    // ---- Phase D: s_out1 = merged1 @ Wso1  (bf16 MFMA, K=352 padded) ----
    {
        const int w = t >> 6, lane = t & 63, lq = lane >> 4, ln = lane & 15;
        f32x4 acc00 = {0,0,0,0}, acc01 = {0,0,0,0}, acc10 = {0,0,0,0}, acc11 = {0,0,0,0};
        const ushortT* a0p = msh + ln * 376 + lq * 8;
        const ushortT* a1p = msh + (16 + ln) * 376 + lq * 8;
        const ushortT* b0p = W1T + (w * 32 + ln) * 352 + lq * 8;
        const ushortT* b1p = W1T + (w * 32 + 16 + ln) * 352 + lq * 8;
        #pragma unroll 2
        for (int ks = 0; ks < 11; ++ks) {
            short8 a0 = *(const short8*)(a0p + ks * 32);
            short8 a1 = *(const short8*)(a1p + ks * 32);
            short8 b0 = *(const short8*)(b0p + ks * 32);
            short8 b1 = *(const short8*)(b1p + ks * 32);
            acc00 = __builtin_amdgcn_mfma_f32_16x16x32_bf16(a0, b0, acc00, 0, 0, 0);
            acc01 = __builtin_amdgcn_mfma_f32_16x16x32_bf16(a0, b1, acc01, 0, 0, 0);
            acc10 = __builtin_amdgcn_mfma_f32_16x16x32_bf16(a1, b0, acc10, 0, 0, 0);
            acc11 = __builtin_amdgcn_mfma_f32_16x16x32_bf16(a1, b1, acc11, 0, 0, 0);
        }
        __syncthreads();   // msh dead; safe to overwrite via gbuf/v1/... aliases later
        const int n0 = w * 32 + ln, n1 = n0 + 16;
        float bi0 = b1so[n0], bi1 = b1so[n1];
        #pragma unroll
        for (int r = 0; r < 4; ++r) {
            int m0 = lq * 4 + r;
            m2[m0 * 168 + n0]        = f2b(siluf_(acc00[r] + bi0));
            m2[m0 * 168 + n1]        = f2b(siluf_(acc01[r] + bi1));
            m2[(16 + m0) * 168 + n0] = f2b(siluf_(acc10[r] + bi0));
            m2[(16 + m0) * 168 + n1] = f2b(siluf_(acc11[r] + bi1));
        }
    }
    __syncthreads();

    // ---- Phase E1: gate1 = sigmoid(s1 @ W1g + b1g) ----
    for (int i = t; i < 512; i += 256) {
        int e = i >> 4, o = i & 15;
        float sum = b1g[o];
        #pragma unroll 4
        for (int c = 0; c < 128; ++c) sum = fmaf(b2f(m2[e * 168 + c]), W1g[c * 16 + o], sum);
        gbuf[e * 16 + o] = sigmoidf_(sum);
    }
    __syncthreads();

    // ---- Phase E2: v1 = (vhid1 @ W1up) * gate1 ----
    for (int i = t; i < 1536; i += 256) {
        int e = i / 48, r = i - e * 48, o = r / 3, sp = r - o * 3;
        float sum = 0.f;
        #pragma unroll 4
        for (int h = 0; h < 36; ++h) sum = fmaf(b2f(vhid[e * 120 + sp * 40 + h]), W1up[h * 16 + o], sum);
        v1[e * 48 + o * 3 + sp] = sum * gbuf[e * 16 + o];
    }
    __syncthreads();

    // ---- Phase G: v_hid2 / v_frames2 ----
    for (int i = t; i < 1824; i += 256) {          // 32*3*19
        int e = i / 57, r = i - e * 57, sp = r / 19, h = r - sp * 19;
        float sum = 0.f;
        if (h < 16) {
            #pragma unroll
            for (int c = 0; c < 16; ++c) sum = fmaf(v1[e * 48 + c * 3 + sp], W2d[c * 16 + h], sum);
            vhid2[e * 48 + sp * 16 + h] = sum;
        } else {
            int a = h - 16;
            #pragma unroll
            for (int c = 0; c < 16; ++c) sum = fmaf(v1[e * 48 + c * 3 + sp], W2f[c * 3 + a], sum);
            vfr2[e * 9 + sp * 3 + a] = sum;
        }
    }
    __syncthreads();

    // ---- Phase H: norm2 + local2 + K-pad zero into m2 rows 128..159 ----
    for (int i = t; i < 1024; i += 256) {
        if (i < 512) {
            int e = i >> 4, h = i & 15;
            float a0 = vhid2[e * 48 + h], a1 = vhid2[e * 48 + 16 + h], a2 = vhid2[e * 48 + 32 + h];
            m2[e * 168 + 128 + h] = f2b(sqrtf(fmaf(a0, a0, fmaf(a1, a1, fmaf(a2, a2, 1e-8f)))));
        } else if (i < 800) {
            int j = i - 512, e = j / 9, r = j - e * 9, a = r / 3, b = r - a * 3;
            float x = fr[e * 9 + b * 3 + 0] * vfr2[e * 9 + 0 + a]
                    + fr[e * 9 + b * 3 + 1] * vfr2[e * 9 + 3 + a]
                    + fr[e * 9 + b * 3 + 2] * vfr2[e * 9 + 6 + a];
            m2[e * 168 + 144 + r] = f2b(x);
        } else {
            int j = i - 800, e = j / 7, k = j - e * 7;   // 32*7 = 224 zeros (153..159)
            m2[e * 168 + 153 + k] = 0;
        }
    }
    __syncthreads();

    // ---- Phase I: s_out2 = merged2 @ Wso2  (bf16 MFMA, K=160 padded) ----
    {
        const int w = t >> 6, lane = t & 63, lq = lane >> 4, ln = lane & 15;
        f32x4 acc00 = {0,0,0,0}, acc01 = {0,0,0,0}, acc10 = {0,0,0,0}, acc11 = {0,0,0,0};
        const ushortT* a0p = m2 + ln * 168 + lq * 8;
        const ushortT* a1p = m2 + (16 + ln) * 168 + lq * 8;
        const ushortT* b0p = W2T + (w * 32 + ln) * 160 + lq * 8;
        const ushortT* b1p = W2T + (w * 32 + 16 + ln) * 160 + lq * 8;
        #pragma unroll
        for (int ks = 0; ks < 5; ++ks) {
            short8 a0 = *(const short8*)(a0p + ks * 32);
            short8 a1 = *(const short8*)(a1p + ks * 32);
            short8 b0 = *(const short8*)(b0p + ks * 32);
            short8 b1 = *(const short8*)(b1p + ks * 32);
            acc00 = __builtin_amdgcn_mfma_f32_16x16x32_bf16(a0, b0, acc00, 0, 0, 0);
            acc01 = __builtin_amdgcn_mfma_f32_16x16x32_bf16(a0, b1, acc01, 0, 0, 0);
            acc10 = __builtin_amdgcn_mfma_f32_16x16x32_bf16(a1, b0, acc10, 0, 0, 0);
            acc11 = __builtin_amdgcn_mfma_f32_16x16x32_bf16(a1, b1, acc11, 0, 0, 0);
        }
        const int n0 = w * 32 + ln, n1 = n0 + 16;
        float bi0 = b2so[n0], bi1 = b2so[n1];
        #pragma unroll
        for (int r = 0; r < 4; ++r) {
            int m0 = lq * 4 + r;
            s2s[m0 * 136 + n0]        = f2b(siluf_(acc00[r] + bi0));
            s2s[m0 * 136 + n1]        = f2b(siluf_(acc01[r] + bi1));
            s2s[(16 + m0) * 136 + n0] = f2b(siluf_(acc10[r] + bi0));
            s2s[(16 + m0) * 136 + n1] = f2b(siluf_(acc11[r] + bi1));
        }
    }
    __syncthreads();

    // ---- Phase J1: gate2 ----
    for (int i = t; i < 512; i += 256) {
        int e = i >> 4, o = i & 15;
        float sum = b2g[o];
        #pragma unroll 4
        for (int c = 0; c < 128; ++c) sum = fmaf(b2f(s2s[e * 136 + c]), W2g[c * 16 + o], sum);
        gbuf[e * 16 + o] = sigmoidf_(sum);
    }
    __syncthreads();

    // ---- Phase J2: v1 += (vhid2 @ W2up) * gate2 ;  Phase K: attention ----
    for (int i = t; i < 1536; i += 256) {
        int e = i / 48, r = i - e * 48, o = r / 3, sp = r - o * 3;
        float sum = 0.f;
        #pragma unroll
        for (int h = 0; h < 16; ++h) sum = fmaf(vhid2[e * 48 + sp * 16 + h], W2up[h * 16 + o], sum);
        v1[e * 48 + o * 3 + sp] += sum * gbuf[e * 16 + o];
    }
    {
        int e = t >> 3, c0 = (t & 7) * 16;
        float sum = 0.f;
        #pragma unroll
        for (int c = c0; c < c0 + 16; ++c)
            sum = fmaf(b2f(m2[e * 168 + c]) + b2f(s2s[e * 136 + c]), attW[c], sum);
        sum += __shfl_xor(sum, 4);
        sum += __shfl_xor(sum, 2);
        sum += __shfl_xor(sum, 1);
        if ((t & 7) == 0) attn[e] = sigmoidf_(sum + attb[0]);
    }
    __syncthreads();

    // ---- Phase L: scatter-add to destination nodes ----
    for (int i = t; i < 32 * 176; i += 256) {
        int e = i / 176, j = i - e * 176;
        float val;
        if (j < 128) val = (b2f(m2[e * 168 + j]) + b2f(s2s[e * 136 + j])) * attn[e];
        else         val = v1[e * 48 + (j - 128)];
        atomicAdd(&out[rowb[e] * 176 + j], val);
    }
}

extern "C" void kernel_launch(void* const* d_in, const int* in_sizes, int n_in,
                              void* d_out, int out_size, void* d_ws, size_t ws_size,
                              hipStream_t stream) {
    const float* node_s = (const float*)d_in[0];
    const float* node_v = (const float*)d_in[1];
    const float* edge_s = (const float*)d_in[2];
    const float* edge_v = (const float*)d_in[3];
    const float* frames = (const float*)d_in[4];
    const float* W1d  = (const float*)d_in[5];
    const float* W1f  = (const float*)d_in[6];
    const float* W1so = (const float*)d_in[7];
    const float* b1so = (const float*)d_in[8];
    const float* W1up = (const float*)d_in[9];
    const float* W1g  = (const float*)d_in[10];
    const float* b1g  = (const float*)d_in[11];
    const float* W2d  = (const float*)d_in[12];
    const float* W2f  = (const float*)d_in[13];
    const float* W2so = (const float*)d_in[14];
    const float* b2so = (const float*)d_in[15];
    const float* W2up = (const float*)d_in[16];
    const float* W2g  = (const float*)d_in[17];
    const float* b2g  = (const float*)d_in[18];
    const float* attW = (const float*)d_in[19];
    const float* attb = (const float*)d_in[20];
    const void*  eidx = d_in[21];

    float* out = (float*)d_out;
    ushortT* ws16 = (ushortT*)d_ws;
    const ushortT* W1T = ws16;
    const ushortT* W2T = ws16 + 45056;

    // d_out is re-poisoned before every timed launch — zero it ourselves.
    hipMemsetAsync(out, 0, (size_t)out_size * sizeof(float), stream);

    prep_kernel<<<256, 256, 0, stream>>>(W1so, W2so, ws16);

    edge_kernel<<<E_TOT / EPB, 256, 0, stream>>>(
        node_s, node_v, edge_s, edge_v, frames,
        W1d, W1f, b1so, W1up, W1g, b1g,
        W2d, W2f, b2so, W2up, W2g, b2g,
        attW, attb, W1T, W2T, eidx, out);
}

// Round 4
// 354.194 us; speedup vs baseline: 6.1328x; 2.6267x over previous
//
#include <hip/hip_runtime.h>
#include <hip/hip_bf16.h>

#define E_TOT 160000
#define NN    10000
#define EPB   32      // edges per block (MFMA M-tiles of 16; vectors use 96 = 3*32 rows)

typedef unsigned short ushortT;
typedef unsigned int   uintT;
typedef __attribute__((ext_vector_type(8))) short short8;
typedef __attribute__((ext_vector_type(4))) float f32x4;

__device__ __forceinline__ float sigmoidf_(float x) { return 1.0f / (1.0f + __expf(-x)); }
__device__ __forceinline__ float siluf_(float x) { return x * sigmoidf_(x); }

__device__ __forceinline__ ushortT f2b(float f) {
    union { float f; uintT u; } x; x.f = f;
    uintT r = x.u + 0x7fffu + ((x.u >> 16) & 1u);
    return (ushortT)(r >> 16);
}
__device__ __forceinline__ float b2f(ushortT h) {
    union { uintT u; float f; } x; x.u = ((uintT)h) << 16; return x.f;
}

// ---- workspace layout (ushort offsets) ----
// W1soT [128][352] @0        W2soT [128][160] @45056
// W1dfT [48][64]   @65536    W1gT  [16][128]  @68608
// W1upT [16][64]   @70656    W2dfT [32][32]   @71680
// W2gT  [16][128]  @72704    W2upT [16][32]   @74752   -> total 75264 ush
#define OFF_W1SO 0
#define OFF_W2SO 45056
#define OFF_W1DF 65536
#define OFF_W1G  68608
#define OFF_W1UP 70656
#define OFF_W2DF 71680
#define OFF_W2G  72704
#define OFF_W2UP 74752

__global__ __launch_bounds__(256) void prep_kernel(
    const float* __restrict__ W1so, const float* __restrict__ W2so,
    const float* __restrict__ W1d,  const float* __restrict__ W1f,
    const float* __restrict__ W1g,  const float* __restrict__ W1up,
    const float* __restrict__ W2d,  const float* __restrict__ W2f,
    const float* __restrict__ W2g,  const float* __restrict__ W2up,
    ushortT* __restrict__ ws)
{
    int i = blockIdx.x * 256 + threadIdx.x;    // grid 294*256 = 75264 exactly
    if (i < OFF_W2SO) {                        // W1soT [n=128][k=352], k<333 real
        int n = i / 352, k = i - n * 352;
        ws[i] = (k < 333) ? f2b(W1so[k * 128 + n]) : (ushortT)0;
    } else if (i < OFF_W1DF) {                 // W2soT [128][160], k<153 real
        int j = i - OFF_W2SO, n = j / 160, k = j - n * 160;
        ws[i] = (k < 153) ? f2b(W2so[k * 128 + n]) : (ushortT)0;
    } else if (i < OFF_W1G) {                  // W1dfT [48][64]: n<36 Wd, 36..38 Wf, rest 0
        int j = i - OFF_W1DF, n = j / 64, k = j - n * 64;
        float v = 0.f;
        if (k < 36) { if (n < 36) v = W1d[k * 36 + n]; else if (n < 39) v = W1f[k * 3 + (n - 36)]; }
        ws[i] = f2b(v);
    } else if (i < OFF_W1UP) {                 // W1gT [16][128]
        int j = i - OFF_W1G, n = j / 128, k = j - n * 128;
        ws[i] = f2b(W1g[k * 16 + n]);
    } else if (i < OFF_W2DF) {                 // W1upT [16][64], k<36 real
        int j = i - OFF_W1UP, n = j / 64, k = j - n * 64;
        ws[i] = (k < 36) ? f2b(W1up[k * 16 + n]) : (ushortT)0;
    } else if (i < OFF_W2G) {                  // W2dfT [32][32]: n<16 Wd, 16..18 Wf, rest 0; k<16
        int j = i - OFF_W2DF, n = j / 32, k = j - n * 32;
        float v = 0.f;
        if (k < 16) { if (n < 16) v = W2d[k * 16 + n]; else if (n < 19) v = W2f[k * 3 + (n - 16)]; }
        ws[i] = f2b(v);
    } else if (i < OFF_W2UP) {                 // W2gT [16][128]
        int j = i - OFF_W2G, n = j / 128, k = j - n * 128;
        ws[i] = f2b(W2g[k * 16 + n]);
    } else {                                   // W2upT [16][32], k<16 real
        int j = i - OFF_W2UP, n = j / 32, k = j - n * 32;
        ws[i] = (k < 16) ? f2b(W2up[k * 16 + n]) : (ushortT)0;
    }
}

#define MFMA(a, b, c) __builtin_amdgcn_mfma_f32_16x16x32_bf16((a), (b), (c), 0, 0, 0)

// Every contraction on MFMA. LDS overlays: 52224 B -> 3 blocks/CU.
__global__ __launch_bounds__(256, 3) void edge_kernel(
    const float* __restrict__ node_s, const float* __restrict__ node_v,
    const float* __restrict__ edge_s, const float* __restrict__ edge_v,
    const float* __restrict__ frames,
    const float* __restrict__ b1so, const float* __restrict__ b1g,
    const float* __restrict__ b2so, const float* __restrict__ b2g,
    const float* __restrict__ attW, const float* __restrict__ attb,
    const ushortT* __restrict__ wsc,
    const void* __restrict__ eidx, float* __restrict__ out)
{
    const ushortT* W1T   = wsc + OFF_W1SO;
    const ushortT* W2T   = wsc + OFF_W2SO;
    const ushortT* W1dfT = wsc + OFF_W1DF;
    const ushortT* W1gT  = wsc + OFF_W1G;
    const ushortT* W1upT = wsc + OFF_W1UP;
    const ushortT* W2dfT = wsc + OFF_W2DF;
    const ushortT* W2gT  = wsc + OFF_W2G;
    const ushortT* W2upT = wsc + OFF_W2UP;

    // ---- LDS overlay map (bytes) ----
    // [0..23040)    msh [32][360] bf16 (dead after D-MFMA); aliases:
    //               gbuf f32 [32][16] @0 ; v1A bf16 [96][40] @2048 ; vhid2A bf16 [96][40] @9728
    // [23040..36864) mvA [96][72] bf16 (dead after B-MFMA); alias m2 bf16 [32][168] @23040
    // [36864..50688) vhidA [96][72] bf16 (dead after E2-MFMA); alias s2s bf16 [32][136] @36864
    // [50688..) fr f32[32][9], attn[32], rowb[32], colb[32]
    __shared__ __align__(16) char smem[52224];
    ushortT* msh    = (ushortT*)smem;
    float*   gbuf   = (float*)smem;
    ushortT* v1A    = (ushortT*)(smem + 2048);
    ushortT* vhid2A = (ushortT*)(smem + 9728);
    ushortT* mvA    = (ushortT*)(smem + 23040);
    ushortT* m2     = (ushortT*)(smem + 23040);
    ushortT* vhidA  = (ushortT*)(smem + 36864);
    ushortT* s2s    = (ushortT*)(smem + 36864);
    float*   fr     = (float*)(smem + 50688);
    float*   attn   = (float*)(smem + 51840);
    int*     rowb   = (int*)(smem + 51968);
    int*     colb   = (int*)(smem + 52096);

    const int t  = threadIdx.x;
    const int eg = blockIdx.x * EPB;
    const int w  = t >> 6, lane = t & 63, lq = lane >> 4, ln = lane & 15;

    // ---- index load, runtime int32/int64 detection ----
    {
        const int* pi = (const int*)eidx;
        const long long* pl = (const long long*)eidx;
        bool is64 = ((pi[1] | pi[3] | pi[5] | pi[7] |
                      pi[9] | pi[11] | pi[13] | pi[15]) == 0);
        if (t < EPB) {
            int r, c;
            if (is64) { r = (int)pl[eg + t]; c = (int)pl[E_TOT + eg + t]; }
            else      { r = pi[eg + t];      c = pi[E_TOT + eg + t];      }
            rowb[t] = r; colb[t] = c;
        }
    }
    __syncthreads();

    // ==== Phase A: gathers + zero pads ====
    for (int i = t; i < 32 * 72; i += 256) {       // merged1 scalars (bf16) into msh
        int e = i / 72, q = i - e * 72;
        float4 v;
        if (q < 32)      v = ((const float4*)node_s)[rowb[e] * 32 + q];
        else if (q < 40) v = ((const float4*)edge_s)[(eg + e) * 8 + (q - 32)];
        else             v = ((const float4*)node_s)[colb[e] * 32 + (q - 40)];
        uintT lo = ((uintT)f2b(v.y) << 16) | f2b(v.x);
        uintT hi = ((uintT)f2b(v.w) << 16) | f2b(v.z);
        *(uint2*)(msh + e * 360 + q * 4) = make_uint2(lo, hi);
    }
    for (int i = t; i < 608; i += 256) {           // msh K-pad 333..351 = 0
        int e = i / 19, k = 333 + (i - e * 19);
        msh[e * 360 + k] = 0;
    }
    for (int i = t; i < 32 * 108; i += 256) {      // vector gather -> mvA[(sp*32+e)][c]
        int e = i / 108, r = i - e * 108, c = r / 3, sp = r - c * 3;
        float v;
        if (c < 16)      v = node_v[rowb[e] * 48 + c * 3 + sp];
        else if (c < 20) v = edge_v[(eg + e) * 12 + (c - 16) * 3 + sp];
        else             v = node_v[colb[e] * 48 + (c - 20) * 3 + sp];
        mvA[(sp * 32 + e) * 72 + c] = f2b(v);
    }
    for (int i = t; i < 1344; i += 256) {          // mvA cols 36..63 = 0 (uint writes)
        int r = i / 14, cc = 36 + 2 * (i - r * 14);
        *(uintT*)(mvA + r * 72 + cc) = 0;
    }
    for (int i = t; i < 768; i += 256) {           // vhidA cols 48..63 = 0
        int r = i >> 3, cc = 48 + ((i & 7) << 1);
        *(uintT*)(vhidA + r * 72 + cc) = 0;
    }
    for (int i = t; i < 288; i += 256) {
        int e = i / 9, j = i - e * 9;
        fr[e * 9 + j] = frames[(eg + e) * 9 + j];
    }
    __syncthreads();

    // ==== Phase B: [96x64] @ W1dfT[48][64] -> vhidA[96][48] (cols 36..38 = vfr1) ====
    for (int u = w; u < 18; u += 4) {
        int mt = u / 3, nt = u - mt * 3;
        const ushortT* ap = mvA + (mt * 16 + ln) * 72 + lq * 8;
        const ushortT* bp = W1dfT + (nt * 16 + ln) * 64 + lq * 8;
        f32x4 acc = {0.f, 0.f, 0.f, 0.f};
        acc = MFMA(*(const short8*)ap,        *(const short8*)bp,        acc);
        acc = MFMA(*(const short8*)(ap + 32), *(const short8*)(bp + 32), acc);
        ushortT* op = vhidA + (mt * 16 + lq * 4) * 72 + nt * 16 + ln;
        op[0]   = f2b(acc[0]); op[72]  = f2b(acc[1]);
        op[144] = f2b(acc[2]); op[216] = f2b(acc[3]);
    }
    __syncthreads();

    // ==== Phase C: v_norm1 + local1 into msh cols 288..332 ====
    for (int i = t; i < 1440; i += 256) {
        if (i < 1152) {
            int e = i / 36, h = i - e * 36;
            float a0 = b2f(vhidA[e * 72 + h]);
            float a1 = b2f(vhidA[(32 + e) * 72 + h]);
            float a2 = b2f(vhidA[(64 + e) * 72 + h]);
            msh[e * 360 + 288 + h] = f2b(sqrtf(fmaf(a0, a0, fmaf(a1, a1, fmaf(a2, a2, 1e-8f)))));
        } else {
            int j = i - 1152, e = j / 9, r = j - e * 9, a = r / 3, b = r - a * 3;
            float x = fr[e * 9 + b * 3 + 0] * b2f(vhidA[e * 72 + 36 + a])
                    + fr[e * 9 + b * 3 + 1] * b2f(vhidA[(32 + e) * 72 + 36 + a])
                    + fr[e * 9 + b * 3 + 2] * b2f(vhidA[(64 + e) * 72 + 36 + a]);
            msh[e * 360 + 324 + r] = f2b(x);
        }
    }
    __syncthreads();

    // ==== Phase D: s_out1 = msh[32][352] @ W1soT -> m2 cols 0..127 (silu) ====
    {
        f32x4 acc00 = {0,0,0,0}, acc01 = {0,0,0,0}, acc10 = {0,0,0,0}, acc11 = {0,0,0,0};
        const ushortT* a0p = msh + ln * 360 + lq * 8;
        const ushortT* a1p = msh + (16 + ln) * 360 + lq * 8;
        const ushortT* b0p = W1T + (w * 32 + ln) * 352 + lq * 8;
        const ushortT* b1p = W1T + (w * 32 + 16 + ln) * 352 + lq * 8;
        #pragma unroll 2
        for (int ks = 0; ks < 11; ++ks) {
            short8 a0 = *(const short8*)(a0p + ks * 32);
            short8 a1 = *(const short8*)(a1p + ks * 32);
            short8 b0 = *(const short8*)(b0p + ks * 32);
            short8 b1 = *(const short8*)(b1p + ks * 32);
            acc00 = MFMA(a0, b0, acc00); acc01 = MFMA(a0, b1, acc01);
            acc10 = MFMA(a1, b0, acc10); acc11 = MFMA(a1, b1, acc11);
        }
        const int n0 = w * 32 + ln, n1 = n0 + 16;
        float bi0 = b1so[n0], bi1 = b1so[n1];
        #pragma unroll
        for (int r = 0; r < 4; ++r) {
            int m0 = lq * 4 + r;
            m2[m0 * 168 + n0]        = f2b(siluf_(acc00[r] + bi0));
            m2[m0 * 168 + n1]        = f2b(siluf_(acc01[r] + bi1));
            m2[(16 + m0) * 168 + n0] = f2b(siluf_(acc10[r] + bi0));
            m2[(16 + m0) * 168 + n1] = f2b(siluf_(acc11[r] + bi1));
        }
    }
    __syncthreads();

    // ==== Phase E: E2 = vhidA @ W1upT (raw v1); E1 = s1 @ W1gT (gate1, waves 2-3) ====
    f32x4 e2a0 = {0,0,0,0}, e2a1 = {0,0,0,0};
    {
        {   // E2 unit 0: mt = w
            const ushortT* ap = vhidA + (w * 16 + ln) * 72 + lq * 8;
            const ushortT* bp = W1upT + ln * 64 + lq * 8;
            e2a0 = MFMA(*(const short8*)ap,        *(const short8*)bp,        e2a0);
            e2a0 = MFMA(*(const short8*)(ap + 32), *(const short8*)(bp + 32), e2a0);
        }
        if (w < 2) {   // E2 unit 1: mt = w+4
            const ushortT* ap = vhidA + ((w + 4) * 16 + ln) * 72 + lq * 8;
            const ushortT* bp = W1upT + ln * 64 + lq * 8;
            e2a1 = MFMA(*(const short8*)ap,        *(const short8*)bp,        e2a1);
            e2a1 = MFMA(*(const short8*)(ap + 32), *(const short8*)(bp + 32), e2a1);
        } else {       // E1: gate1, mt = w-2
            int mt = w - 2;
            const ushortT* ap = m2 + (mt * 16 + ln) * 168;
            const ushortT* bp = W1gT + ln * 128;
            f32x4 acc = {0,0,0,0};
            #pragma unroll
            for (int ks = 0; ks < 4; ++ks)
                acc = MFMA(*(const short8*)(ap + ks * 32 + lq * 8),
                           *(const short8*)(bp + ks * 32 + lq * 8), acc);
            float bi = b1g[ln];
            #pragma unroll
            for (int r = 0; r < 4; ++r)
                gbuf[(mt * 16 + lq * 4 + r) * 16 + ln] = sigmoidf_(acc[r] + bi);
        }
        for (int i = t; i < 768; i += 256) {   // v1A cols 16..31 = 0 (G K-pad)
            int r = i >> 3, cc = 16 + ((i & 7) << 1);
            *(uintT*)(v1A + r * 40 + cc) = 0;
        }
    }
    __syncthreads();

    // ==== E2 epilogue: v1A = raw * gate1 (bf16) ====
    {
        #pragma unroll
        for (int r = 0; r < 4; ++r) {
            int row = w * 16 + lq * 4 + r;
            v1A[row * 40 + ln] = f2b(e2a0[r] * gbuf[(row & 31) * 16 + ln]);
        }
        if (w < 2) {
            #pragma unroll
            for (int r = 0; r < 4; ++r) {
                int row = (w + 4) * 16 + lq * 4 + r;
                v1A[row * 40 + ln] = f2b(e2a1[r] * gbuf[(row & 31) * 16 + ln]);
            }
        }
    }
    __syncthreads();

    // ==== Phase G: v1A[96][32] @ W2dfT[32][32] -> vhid2A[96][32] (16..18 = vfr2, 19..31 = 0) ====
    for (int u = w; u < 12; u += 4) {
        int mt = u >> 1, nt = u & 1;
        const ushortT* ap = v1A + (mt * 16 + ln) * 40 + lq * 8;
        const ushortT* bp = W2dfT + (nt * 16 + ln) * 32 + lq * 8;
        f32x4 acc = {0,0,0,0};
        acc = MFMA(*(const short8*)ap, *(const short8*)bp, acc);
        ushortT* op = vhid2A + (mt * 16 + lq * 4) * 40 + nt * 16 + ln;
        op[0]  = f2b(acc[0]); op[40]  = f2b(acc[1]);
        op[80] = f2b(acc[2]); op[120] = f2b(acc[3]);
    }
    __syncthreads();

    // ==== Phase H: norm2 + local2 + zeros into m2 cols 128..159 ====
    for (int i = t; i < 1024; i += 256) {
        if (i < 512) {
            int e = i >> 4, h = i & 15;
            float a0 = b2f(vhid2A[e * 40 + h]);
            float a1 = b2f(vhid2A[(32 + e) * 40 + h]);
            float a2 = b2f(vhid2A[(64 + e) * 40 + h]);
            m2[e * 168 + 128 + h] = f2b(sqrtf(fmaf(a0, a0, fmaf(a1, a1, fmaf(a2, a2, 1e-8f)))));
        } else if (i < 800) {
            int j = i - 512, e = j / 9, r = j - e * 9, a = r / 3, b = r - a * 3;
            float x = fr[e * 9 + b * 3 + 0] * b2f(vhid2A[e * 40 + 16 + a])
                    + fr[e * 9 + b * 3 + 1] * b2f(vhid2A[(32 + e) * 40 + 16 + a])
                    + fr[e * 9 + b * 3 + 2] * b2f(vhid2A[(64 + e) * 40 + 16 + a]);
            m2[e * 168 + 144 + r] = f2b(x);
        } else {
            int j = i - 800, e = j / 7, k = j - e * 7;
            m2[e * 168 + 153 + k] = 0;
        }
    }
    __syncthreads();

    // ==== Phase I: s_out2 = m2[32][160] @ W2soT -> s2s (silu) ====
    {
        f32x4 acc00 = {0,0,0,0}, acc01 = {0,0,0,0}, acc10 = {0,0,0,0}, acc11 = {0,0,0,0};
        const ushortT* a0p = m2 + ln * 168 + lq * 8;
        const ushortT* a1p = m2 + (16 + ln) * 168 + lq * 8;
        const ushortT* b0p = W2T + (w * 32 + ln) * 160 + lq * 8;
        const ushortT* b1p = W2T + (w * 32 + 16 + ln) * 160 + lq * 8;
        #pragma unroll
        for (int ks = 0; ks < 5; ++ks) {
            short8 a0 = *(const short8*)(a0p + ks * 32);
            short8 a1 = *(const short8*)(a1p + ks * 32);
            short8 b0 = *(const short8*)(b0p + ks * 32);
            short8 b1 = *(const short8*)(b1p + ks * 32);
            acc00 = MFMA(a0, b0, acc00); acc01 = MFMA(a0, b1, acc01);
            acc10 = MFMA(a1, b0, acc10); acc11 = MFMA(a1, b1, acc11);
        }
        const int n0 = w * 32 + ln, n1 = n0 + 16;
        float bi0 = b2so[n0], bi1 = b2so[n1];
        #pragma unroll
        for (int r = 0; r < 4; ++r) {
            int m0 = lq * 4 + r;
            s2s[m0 * 136 + n0]        = f2b(siluf_(acc00[r] + bi0));
            s2s[m0 * 136 + n1]        = f2b(siluf_(acc01[r] + bi1));
            s2s[(16 + m0) * 136 + n0] = f2b(siluf_(acc10[r] + bi0));
            s2s[(16 + m0) * 136 + n1] = f2b(siluf_(acc11[r] + bi1));
        }
    }
    __syncthreads();

    // ==== Phase J: J2 = vhid2A @ W2upT (raw v2); J1 = s2 @ W2gT (gate2); attention ====
    f32x4 j2a0 = {0,0,0,0}, j2a1 = {0,0,0,0};
    {
        {   // J2 unit 0: mt = w
            const ushortT* ap = vhid2A + (w * 16 + ln) * 40 + lq * 8;
            const ushortT* bp = W2upT + ln * 32 + lq * 8;
            j2a0 = MFMA(*(const short8*)ap, *(const short8*)bp, j2a0);
        }
        if (w < 2) {   // J2 unit 1: mt = w+4
            const ushortT* ap = vhid2A + ((w + 4) * 16 + ln) * 40 + lq * 8;
            const ushortT* bp = W2upT + ln * 32 + lq * 8;
            j2a1 = MFMA(*(const short8*)ap, *(const short8*)bp, j2a1);
        } else {       // J1: gate2, mt = w-2
            int mt = w - 2;
            const ushortT* ap = s2s + (mt * 16 + ln) * 136;
            const ushortT* bp = W2gT + ln * 128;
            f32x4 acc = {0,0,0,0};
            #pragma unroll
            for (int ks = 0; ks < 4; ++ks)
                acc = MFMA(*(const short8*)(ap + ks * 32 + lq * 8),
                           *(const short8*)(bp + ks * 32 + lq * 8), acc);
            float bi = b2g[ln];
            #pragma unroll
            for (int r = 0; r < 4; ++r)
                gbuf[(mt * 16 + lq * 4 + r) * 16 + ln] = sigmoidf_(acc[r] + bi);
        }
        // attention: sigmoid((s1+s2) . attW + b), 8 threads per edge
        {
            int e = t >> 3, c0 = (t & 7) * 16;
            float sum = 0.f;
            #pragma unroll
            for (int c = c0; c < c0 + 16; ++c)
                sum = fmaf(b2f(m2[e * 168 + c]) + b2f(s2s[e * 136 + c]), attW[c], sum);
            sum += __shfl_xor(sum, 4);
            sum += __shfl_xor(sum, 2);
            sum += __shfl_xor(sum, 1);
            if ((t & 7) == 0) attn[e] = sigmoidf_(sum + attb[0]);
        }
    }
    __syncthreads();

    // ==== J2 epilogue: v_final = v1 + raw_v2 * gate2 (in-place in v1A) ====
    {
        #pragma unroll
        for (int r = 0; r < 4; ++r) {
            int row = w * 16 + lq * 4 + r;
            float vfin = b2f(v1A[row * 40 + ln]) + j2a0[r] * gbuf[(row & 31) * 16 + ln];
            v1A[row * 40 + ln] = f2b(vfin);
        }
        if (w < 2) {
            #pragma unroll
            for (int r = 0; r < 4; ++r) {
                int row = (w + 4) * 16 + lq * 4 + r;
                float vfin = b2f(v1A[row * 40 + ln]) + j2a1[r] * gbuf[(row & 31) * 16 + ln];
                v1A[row * 40 + ln] = f2b(vfin);
            }
        }
    }
    __syncthreads();

    // ==== Phase L: scatter-add to destination nodes ====
    for (int i = t; i < 32 * 176; i += 256) {
        int e = i / 176, j = i - e * 176;
        float val;
        if (j < 128) {
            val = (b2f(m2[e * 168 + j]) + b2f(s2s[e * 136 + j])) * attn[e];
        } else {
            int r = j - 128, o = r / 3, sp = r - o * 3;
            val = b2f(v1A[(sp * 32 + e) * 40 + o]);
        }
        atomicAdd(&out[rowb[e] * 176 + j], val);
    }
}

extern "C" void kernel_launch(void* const* d_in, const int* in_sizes, int n_in,
                              void* d_out, int out_size, void* d_ws, size_t ws_size,
                              hipStream_t stream) {
    const float* node_s = (const float*)d_in[0];
    const float* node_v = (const float*)d_in[1];
    const float* edge_s = (const float*)d_in[2];
    const float* edge_v = (const float*)d_in[3];
    const float* frames = (const float*)d_in[4];
    const float* W1d  = (const float*)d_in[5];
    const float* W1f  = (const float*)d_in[6];
    const float* W1so = (const float*)d_in[7];
    const float* b1so = (const float*)d_in[8];
    const float* W1up = (const float*)d_in[9];
    const float* W1g  = (const float*)d_in[10];
    const float* b1g  = (const float*)d_in[11];
    const float* W2d  = (const float*)d_in[12];
    const float* W2f  = (const float*)d_in[13];
    const float* W2so = (const float*)d_in[14];
    const float* b2so = (const float*)d_in[15];
    const float* W2up = (const float*)d_in[16];
    const float* W2g  = (const float*)d_in[17];
    const float* b2g  = (const float*)d_in[18];
    const float* attW = (const float*)d_in[19];
    const float* attb = (const float*)d_in[20];
    const void*  eidx = d_in[21];

    float* out = (float*)d_out;
    ushortT* ws16 = (ushortT*)d_ws;

    hipMemsetAsync(out, 0, (size_t)out_size * sizeof(float), stream);

    prep_kernel<<<294, 256, 0, stream>>>(W1so, W2so, W1d, W1f, W1g, W1up,
                                         W2d, W2f, W2g, W2up, ws16);

    edge_kernel<<<E_TOT / EPB, 256, 0, stream>>>(
        node_s, node_v, edge_s, edge_v, frames,
        b1so, b1g, b2so, b2g, attW, attb,
        (const ushortT*)ws16, eidx, out);
}